// Round 2
// baseline (10226.832 us; speedup 1.0000x reference)
//
#include <hip/hip_runtime.h>

// RVQ inference: B=16, C=64, N=4096, Q=8, K=8192, fp32.
// Outputs (concat, float32): out[B,C,N], indices[B,N,Q] (as float), mean loss (1).
// ws layout: [0 .. Q*K) = cbsq (float), [Q*K] = loss accumulator (float).

constexpr int Bn = 16, Cn = 64, Nn = 4096, Qn = 8, Kn = 8192;
constexpr int PTS = 64;                 // points per block (one per lane)
constexpr int CHUNK = 128;              // codebook rows staged per LDS chunk
constexpr int NCHUNK = Kn / CHUNK;      // 64
constexpr int ROWS_PER_WAVE = CHUNK / 4;// 32

__global__ __launch_bounds__(256) void cbsq_kernel(const float* __restrict__ cb,
                                                   float* __restrict__ ws) {
    int row = blockIdx.x * 256 + threadIdx.x;   // 0 .. Q*K-1
    if (row == 0) ws[Qn * Kn] = 0.0f;           // zero loss accumulator (stream-ordered before main)
    if (row < Qn * Kn) {
        const float4* r = (const float4*)(cb + (size_t)row * Cn);
        float s = 0.0f;
#pragma unroll
        for (int i = 0; i < 16; ++i) {
            float4 v = r[i];
            s = fmaf(v.x, v.x, s); s = fmaf(v.y, v.y, s);
            s = fmaf(v.z, v.z, s); s = fmaf(v.w, v.w, s);
        }
        ws[row] = s;
    }
}

// __launch_bounds__(256, 2): min 2 waves/EU -> VGPR budget 256. Round-1 used
// (256,4) and the allocator targeted 64 VGPRs, spilling res[64] to scratch
// (WRITE_SIZE 153 MB vs 19 MB ideal). res[] must live in registers.
__global__ __launch_bounds__(256, 2) void rvq_kernel(
    const float* __restrict__ x, const float* __restrict__ cb,
    const float* __restrict__ cbsq, float* __restrict__ out,
    float* __restrict__ loss_acc) {
    __shared__ float lds_cb[CHUNK * Cn];
    __shared__ float lds_sq[CHUNK];
    __shared__ float red_d[4][PTS];
    __shared__ int   red_k[4][PTS];

    const int tid  = threadIdx.x;
    const int wave = tid >> 6;
    const int lane = tid & 63;
    const int gp   = blockIdx.x * PTS + lane;   // global point id = b*N + n
    const int b    = gp >> 12;                  // N = 4096
    const int n    = gp & (Nn - 1);
    const float* xp = x + (size_t)b * Cn * Nn + n;

    float res[Cn];
#pragma unroll
    for (int c = 0; c < Cn; ++c) res[c] = xp[(size_t)c * Nn];

    float loss_pt = 0.0f;

    for (int q = 0; q < Qn; ++q) {
        const float* cbq = cb + (size_t)q * Kn * Cn;
        float best_d = 3.4e38f;
        int   best_k = 0;

        for (int ch = 0; ch < NCHUNK; ++ch) {
            __syncthreads();                      // previous chunk fully consumed
            // stage 128 rows (32 KB), coalesced float4
            const float4* src = (const float4*)(cbq + (size_t)ch * CHUNK * Cn);
            float4* dst = (float4*)lds_cb;
#pragma unroll
            for (int i = 0; i < (CHUNK * Cn / 4) / 256; ++i)
                dst[tid + i * 256] = src[tid + i * 256];
            if (tid < CHUNK) lds_sq[tid] = cbsq[q * Kn + ch * CHUNK + tid];
            __syncthreads();

            const int rbase = wave * ROWS_PER_WAVE;
            for (int r0 = 0; r0 < ROWS_PER_WAVE; r0 += 4) {
                const float4* p0 = (const float4*)(lds_cb + (rbase + r0 + 0) * Cn);
                const float4* p1 = (const float4*)(lds_cb + (rbase + r0 + 1) * Cn);
                const float4* p2 = (const float4*)(lds_cb + (rbase + r0 + 2) * Cn);
                const float4* p3 = (const float4*)(lds_cb + (rbase + r0 + 3) * Cn);
                float a0 = 0.f, a1 = 0.f, a2 = 0.f, a3 = 0.f;
#pragma unroll
                for (int i = 0; i < 16; ++i) {
                    float4 v0 = p0[i], v1 = p1[i], v2 = p2[i], v3 = p3[i];
                    const float w0 = res[4 * i + 0], w1 = res[4 * i + 1];
                    const float w2 = res[4 * i + 2], w3 = res[4 * i + 3];
                    a0 = fmaf(w0, v0.x, a0); a0 = fmaf(w1, v0.y, a0);
                    a0 = fmaf(w2, v0.z, a0); a0 = fmaf(w3, v0.w, a0);
                    a1 = fmaf(w0, v1.x, a1); a1 = fmaf(w1, v1.y, a1);
                    a1 = fmaf(w2, v1.z, a1); a1 = fmaf(w3, v1.w, a1);
                    a2 = fmaf(w0, v2.x, a2); a2 = fmaf(w1, v2.y, a2);
                    a2 = fmaf(w2, v2.z, a2); a2 = fmaf(w3, v2.w, a2);
                    a3 = fmaf(w0, v3.x, a3); a3 = fmaf(w1, v3.y, a3);
                    a3 = fmaf(w2, v3.z, a3); a3 = fmaf(w3, v3.w, a3);
                }
                const int kb = ch * CHUNK + rbase + r0;
                float d0 = lds_sq[rbase + r0 + 0] - 2.0f * a0;
                float d1 = lds_sq[rbase + r0 + 1] - 2.0f * a1;
                float d2 = lds_sq[rbase + r0 + 2] - 2.0f * a2;
                float d3 = lds_sq[rbase + r0 + 3] - 2.0f * a3;
                // strict < keeps the FIRST (lowest-k) minimum, matching jnp.argmin
                if (d0 < best_d) { best_d = d0; best_k = kb + 0; }
                if (d1 < best_d) { best_d = d1; best_k = kb + 1; }
                if (d2 < best_d) { best_d = d2; best_k = kb + 2; }
                if (d3 < best_d) { best_d = d3; best_k = kb + 3; }
            }
        }

        // combine the 4 wave-local argmins (K was split 4-way across waves)
        red_d[wave][lane] = best_d;
        red_k[wave][lane] = best_k;
        __syncthreads();
        float bd = red_d[0][lane];
        int   bk = red_k[0][lane];
#pragma unroll
        for (int w = 1; w < 4; ++w) {
            float d2w = red_d[w][lane];
            int   k2w = red_k[w][lane];
            if (d2w < bd || (d2w == bd && k2w < bk)) { bd = d2w; bk = k2w; }
        }

        if (wave == 0)
            out[(size_t)(Bn * Cn * Nn) + (size_t)gp * Qn + q] = (float)bk;

        // residual update (gather winning code row; codebook is L2-hot)
        const float4* crow = (const float4*)(cbq + (size_t)bk * Cn);
        float ss = 0.0f;
#pragma unroll
        for (int i = 0; i < 16; ++i) {
            float4 v = crow[i];
            res[4 * i + 0] -= v.x; res[4 * i + 1] -= v.y;
            res[4 * i + 2] -= v.z; res[4 * i + 3] -= v.w;
            ss = fmaf(res[4 * i + 0], res[4 * i + 0], ss);
            ss = fmaf(res[4 * i + 1], res[4 * i + 1], ss);
            ss = fmaf(res[4 * i + 2], res[4 * i + 2], ss);
            ss = fmaf(res[4 * i + 3], res[4 * i + 3], ss);
        }
        loss_pt += ss;   // Σ_q |new residual|^2 ; same weight each q
    }

    if (wave == 0) {
        // quantized = x - final residual ; out[b][c][n], coalesced over n (lanes)
#pragma unroll
        for (int c = 0; c < Cn; ++c)
            out[((size_t)b * Cn + c) * Nn + n] = xp[(size_t)c * Nn] - res[c];
        // block loss: wave-64 shuffle reduce, one atomic per block
        float s = loss_pt;
#pragma unroll
        for (int off = 32; off > 0; off >>= 1) s += __shfl_down(s, off, 64);
        if (lane == 0) atomicAdd(loss_acc, s);
    }
}

__global__ void final_kernel(const float* __restrict__ loss_acc,
                             float* __restrict__ out) {
    out[(size_t)Bn * Cn * Nn + (size_t)Bn * Nn * Qn] =
        loss_acc[0] * (1.0f / ((float)Qn * Bn * Nn * Cn));
}

extern "C" void kernel_launch(void* const* d_in, const int* in_sizes, int n_in,
                              void* d_out, int out_size, void* d_ws, size_t ws_size,
                              hipStream_t stream) {
    const float* x  = (const float*)d_in[0];
    const float* cb = (const float*)d_in[1];
    float* out = (float*)d_out;
    float* ws  = (float*)d_ws;

    hipLaunchKernelGGL(cbsq_kernel, dim3((Qn * Kn) / 256), dim3(256), 0, stream, cb, ws);
    hipLaunchKernelGGL(rvq_kernel, dim3((Bn * Nn) / PTS), dim3(256), 0, stream,
                       x, cb, ws, out, ws + Qn * Kn);
    hipLaunchKernelGGL(final_kernel, dim3(1), dim3(1), 0, stream, ws + Qn * Kn, out);
}

// Round 3
// 6571.487 us; speedup vs baseline: 1.5562x; 1.5562x over previous
//
#include <hip/hip_runtime.h>
#include <float.h>

// RVQ inference: B=16, C=64, N=4096, Q=8, K=8192, fp32.
// Round-3 structure: 2-D register-tiled distance GEMM.
//  - Block owns P=128 consecutive points (same b); residuals live in LDS
//    transposed RT[c][p] (x is [B,C,N] so this layout is load-free).
//  - Codebook processed in CH=128-row chunks, staged transposed CBT[c][k]
//    with a register double-buffer (global prefetch during compute).
//  - Each thread computes an 8-point x 8-row tile: per c-step 4 ds_read_b128
//    feed 64 FMAs (vs 1 read/FMA in round 2 -> 16x less LDS issue).
// ws: [0..Q*K) cbsq, [Q*K] loss accumulator.

constexpr int Bn=16, Cn=64, Nn=4096, Qn=8, Kn=8192;
constexpr int P=128, CH=128, NCH=Kn/CH;   // 64 chunks per quantizer
constexpr int STR=132;                    // LDS row stride: 128+4 keeps b128 16B-aligned, <=2-way banks
constexpr int NBLK=Bn*Nn/P;               // 512 blocks = 2 per CU, all resident

__global__ __launch_bounds__(256) void cbsq_kernel(const float* __restrict__ cb,
                                                   float* __restrict__ ws){
  int row = blockIdx.x*256 + threadIdx.x;
  if (row == 0) ws[Qn*Kn] = 0.f;
  if (row < Qn*Kn){
    const float4* r = (const float4*)(cb + (size_t)row*Cn);
    float s = 0.f;
#pragma unroll
    for (int i=0;i<16;++i){ float4 v=r[i];
      s=fmaf(v.x,v.x,s); s=fmaf(v.y,v.y,s); s=fmaf(v.z,v.z,s); s=fmaf(v.w,v.w,s); }
    ws[row]=s;
  }
}

__global__ __launch_bounds__(256,2) void rvq_kernel(
    const float* __restrict__ x, const float* __restrict__ cb,
    const float* __restrict__ cbsq, float* __restrict__ out,
    float* __restrict__ loss_acc){
  __shared__ float RT [Cn*STR];    // residuals, transposed [c][p]
  __shared__ float CBT[Cn*STR];    // codebook chunk, transposed [c][k]; reused as reduce buf
  __shared__ int   bk_sh[P];
  __shared__ float lsum[4];
  float* red_d = CBT;              // [16][128] floats
  int*   red_k = (int*)(CBT + 16*P);

  const int tid  = threadIdx.x;
  const int i4   = (tid & 15) * 4;  // point tile base (cols i4.. and 64+i4..)
  const int jrow = tid >> 4;        // 0..15
  const int j8   = jrow * 8;        // row tile base within chunk
  const int g4   = tid >> 4;        // staging: c-group 0..15
  const int kk16 = tid & 15;        // staging: k sub-index
  const int b    = blockIdx.x >> 5; // 32 blocks per batch elem
  const int n0   = (blockIdx.x & 31) * P;

  const float4* cb4 = (const float4*)cb;

  // ---- RT init from x (coalesced float4 both sides) ----
#pragma unroll
  for (int it=0; it<8; ++it){
    int f = tid + it*256;           // 2048 float4s
    int c = f >> 5, p4 = f & 31;
    float4 v = ((const float4*)(x + ((size_t)b*Cn + c)*Nn + n0))[p4];
    *(float4*)&RT[c*STR + p4*4] = v;
  }

  // ---- preload chunk (q=0, ch=0) into registers ----
  float4 g[8];
#pragma unroll
  for (int l=0;l<8;++l)
    g[l] = cb4[(size_t)(l*16 + kk16)*16 + g4];

  float loss_pt = 0.f;

  for (int q=0; q<Qn; ++q){
    float best_d[8]; int best_k[8];
#pragma unroll
    for (int t=0;t<8;++t){ best_d[t]=FLT_MAX; best_k[t]=0; }

    for (int ch=0; ch<NCH; ++ch){
      __syncthreads();              // CBT free (prev compute / q-epilogue done)
      // stage regs -> CBT transposed (banks 2-way -> free)
#pragma unroll
      for (int l=0;l<8;++l){
        const float* gv = (const float*)&g[l];
        int k = l*16 + kk16;
#pragma unroll
        for (int m=0;m<4;++m) CBT[(g4*4+m)*STR + k] = gv[m];
      }
      __syncthreads();

      // prefetch this chunk's cbsq and the NEXT chunk's codebook rows
      float4 cs0 = *(const float4*)(cbsq + q*Kn + ch*CH + j8);
      float4 cs1 = *(const float4*)(cbsq + q*Kn + ch*CH + j8 + 4);
      int nidx = q*NCH + ch + 1; if (nidx >= Qn*NCH) nidx = 0;  // harmless wrap
      const size_t nrow = (size_t)nidx * CH;
#pragma unroll
      for (int l=0;l<8;++l)
        g[l] = cb4[(nrow + l*16 + kk16)*16 + g4];

      float acc[8][8];
#pragma unroll
      for (int t=0;t<8;++t)
#pragma unroll
        for (int k=0;k<8;++k) acc[t][k]=0.f;

#pragma unroll 2
      for (int c=0;c<Cn;++c){
        float4 r0 = *(const float4*)&RT [c*STR + i4];
        float4 r1 = *(const float4*)&RT [c*STR + 64 + i4];
        float4 b0 = *(const float4*)&CBT[c*STR + j8];
        float4 b1 = *(const float4*)&CBT[c*STR + j8 + 4];
        const float rr[8] = {r0.x,r0.y,r0.z,r0.w, r1.x,r1.y,r1.z,r1.w};
        const float bb[8] = {b0.x,b0.y,b0.z,b0.w, b1.x,b1.y,b1.z,b1.w};
#pragma unroll
        for (int t=0;t<8;++t)
#pragma unroll
          for (int k=0;k<8;++k)
            acc[t][k] = fmaf(rr[t], bb[k], acc[t][k]);
      }

      const int kbase = ch*CH + j8;
      const float cs[8] = {cs0.x,cs0.y,cs0.z,cs0.w, cs1.x,cs1.y,cs1.z,cs1.w};
#pragma unroll
      for (int k=0;k<8;++k){
        float cq = cs[k];
#pragma unroll
        for (int t=0;t<8;++t){
          float d = cq - 2.0f*acc[t][k];     // same expr as rounds 1-2 (passed)
          if (d < best_d[t]){ best_d[t]=d; best_k[t]=kbase+k; }  // strict <, k ascending
        }
      }
    }

    // ---- cross-thread argmin reduce (16 j-threads per point), lex (d,k) ----
    __syncthreads();                // done reading CBT this q; reuse as red bufs
#pragma unroll
    for (int t=0;t<8;++t){
      int p = (t<4) ? (i4 + t) : (64 + i4 + (t-4));
      red_d[jrow*P + p] = best_d[t];
      red_k[jrow*P + p] = best_k[t];
    }
    __syncthreads();
    if (tid < P){
      float bd = red_d[tid]; int bk = red_k[tid];
#pragma unroll
      for (int jj=1; jj<16; ++jj){
        float d = red_d[jj*P + tid]; int kv = red_k[jj*P + tid];
        if (d < bd || (d == bd && kv < bk)){ bd = d; bk = kv; }
      }
      bk_sh[tid] = bk;
      out[(size_t)(Bn*Cn*Nn) + (size_t)(b*Nn + n0 + tid)*Qn + q] = (float)bk;
    }
    __syncthreads();

    // ---- residual update + loss (each (c,p) touched exactly once) ----
    {
      int p = tid & 127, half = tid >> 7;   // half: c in [0,32) or [32,64)
      int bk = bk_sh[p];
      const float4* crow = (const float4*)(cb + ((size_t)q*Kn + bk)*Cn) + half*8;
#pragma unroll
      for (int l=0;l<8;++l){
        float4 v = crow[l];
        int c = half*32 + l*4;
        float r0 = RT[(c+0)*STR + p] - v.x;
        float r1 = RT[(c+1)*STR + p] - v.y;
        float r2 = RT[(c+2)*STR + p] - v.z;
        float r3 = RT[(c+3)*STR + p] - v.w;
        RT[(c+0)*STR + p] = r0; RT[(c+1)*STR + p] = r1;
        RT[(c+2)*STR + p] = r2; RT[(c+3)*STR + p] = r3;
        loss_pt = fmaf(r0,r0,loss_pt); loss_pt = fmaf(r1,r1,loss_pt);
        loss_pt = fmaf(r2,r2,loss_pt); loss_pt = fmaf(r3,r3,loss_pt);
      }
    }
    __syncthreads();                // RT consistent before next q / final out
  }

  // ---- quantized output: out = x - final residual ----
#pragma unroll
  for (int it=0; it<8; ++it){
    int f = tid + it*256;
    int c = f >> 5, p4 = f & 31;
    float4 xv = ((const float4*)(x + ((size_t)b*Cn + c)*Nn + n0))[p4];
    float4 rv = *(const float4*)&RT[c*STR + p4*4];
    float4 o; o.x=xv.x-rv.x; o.y=xv.y-rv.y; o.z=xv.z-rv.z; o.w=xv.w-rv.w;
    ((float4*)(out + ((size_t)b*Cn + c)*Nn + n0))[p4] = o;
  }

  // ---- loss: wave shuffle-reduce, cross-wave via LDS, one atomic/block ----
  float s = loss_pt;
#pragma unroll
  for (int off=32; off>0; off>>=1) s += __shfl_down(s, off, 64);
  if ((tid & 63) == 0) lsum[tid >> 6] = s;
  __syncthreads();
  if (tid == 0) atomicAdd(loss_acc, lsum[0]+lsum[1]+lsum[2]+lsum[3]);
}

__global__ void final_kernel(const float* __restrict__ loss_acc,
                             float* __restrict__ out){
  out[(size_t)Bn*Cn*Nn + (size_t)Bn*Nn*Qn] =
      loss_acc[0] * (1.0f / ((float)Qn * Bn * Nn * Cn));
}

extern "C" void kernel_launch(void* const* d_in, const int* in_sizes, int n_in,
                              void* d_out, int out_size, void* d_ws, size_t ws_size,
                              hipStream_t stream) {
  const float* x  = (const float*)d_in[0];
  const float* cb = (const float*)d_in[1];
  float* out = (float*)d_out;
  float* ws  = (float*)d_ws;

  hipLaunchKernelGGL(cbsq_kernel, dim3((Qn*Kn)/256), dim3(256), 0, stream, cb, ws);
  hipLaunchKernelGGL(rvq_kernel, dim3(NBLK), dim3(256), 0, stream,
                     x, cb, ws, out, ws + Qn*Kn);
  hipLaunchKernelGGL(final_kernel, dim3(1), dim3(1), 0, stream, ws + Qn*Kn, out);
}

// Round 4
// 1820.792 us; speedup vs baseline: 5.6167x; 3.6091x over previous
//
#include <hip/hip_runtime.h>
#include <float.h>

// RVQ inference via MFMA: B=16, C=64, N=4096, Q=8, K=8192, fp32 in/out.
// Distance GEMM in bf16 hi/lo split (3 products, fp32 accumulate) on
// mfma_f32_16x16x32_bf16; top-2 tracking + exact-fp32 rescore when the
// winner margin < TAU guards the argmin against split noise (~1e-4).
// A = codebook frags streamed from L2 (no LDS staging); B = 128 residuals
// persistent in VGPRs; acc init = -0.5*|c|^2 (argmax s == argmin dist).
// ws: shalf (QK f32) | WH (QKC bf16-hi as u16) | WL (lo) | loss (f32).

typedef float f32x4 __attribute__((ext_vector_type(4)));
typedef short s16x8 __attribute__((ext_vector_type(8)));

constexpr int Bn=16, Cn=64, Nn=4096, Qn=8, Kn=8192;
constexpr int P=128;                    // points per block
constexpr int NBLK = Bn*Nn/P;           // 512 blocks = 2/CU
constexpr float TAU = 0.05f;            // rescore margin (error ~1e-4)
constexpr size_t SH_F = (size_t)Qn*Kn;  // shalf floats
constexpr size_t W_U  = (size_t)Qn*Kn*Cn; // WH/WL ushorts

union U8 { s16x8 v; unsigned short u[8]; };

__device__ __forceinline__ unsigned short bf_rtne(float x){
  unsigned int u = __float_as_uint(x);
  unsigned int r = (u + 0x7fffu + ((u>>16)&1u)) >> 16;
  return (unsigned short)r;
}

__global__ __launch_bounds__(256) void prep_kernel(const float* __restrict__ cb,
    float* __restrict__ shalf, unsigned short* __restrict__ WH,
    unsigned short* __restrict__ WL, float* __restrict__ loss){
  int r = blockIdx.x*256 + threadIdx.x;        // 0..Q*K-1, one codebook row
  if (r==0) *loss = 0.f;
  const float* row = cb + (size_t)r*Cn;
  float sq = 0.f;
  for (int c=0;c<Cn;++c){
    float v = row[c]; sq = fmaf(v,v,sq);
    unsigned short h = bf_rtne(v);
    float hf = __uint_as_float((unsigned int)h<<16);
    unsigned short l = bf_rtne(v-hf);
    WH[(size_t)r*Cn+c]=h; WL[(size_t)r*Cn+c]=l;
  }
  shalf[r] = -0.5f*sq;
}

__global__ __launch_bounds__(256,2) void rvq_kernel(
    const float* __restrict__ x, const float* __restrict__ cb,
    const float* __restrict__ shalf,
    const unsigned short* __restrict__ WH, const unsigned short* __restrict__ WL,
    float* __restrict__ out, float* __restrict__ loss_acc){
  // RES4[p*16 + (g ^ (p&15))] holds res[p][4g..4g+3]  (XOR-swizzle: frag reads
  // with 16 rows x 256B stride would otherwise be 16-way bank conflicts)
  __shared__ float4 RES4[P*16];
  __shared__ float  red_s1[4][P]; __shared__ int red_k1[4][P];
  __shared__ float  red_s2[4][P]; __shared__ int red_k2[4][P];
  __shared__ int    bk_sh[P];
  __shared__ float  lsum[4];

  const int tid  = threadIdx.x;
  const int wave = tid>>6, lane = tid&63;
  const int quad = lane>>4, l16 = lane&15;
  const int b    = blockIdx.x>>5;
  const int n0   = (blockIdx.x&31)*P;

  { // ---- RES init from x[B,C,N] (coalesced over p) ----
    int p = tid & (P-1), hc = tid>>7;
    const float* xb = x + ((size_t)b*Cn)*Nn + n0 + p;
#pragma unroll
    for (int l=0;l<8;++l){
      int g = hc*8 + l;
      float4 v;
      v.x = xb[(size_t)(4*g+0)*Nn]; v.y = xb[(size_t)(4*g+1)*Nn];
      v.z = xb[(size_t)(4*g+2)*Nn]; v.w = xb[(size_t)(4*g+3)*Nn];
      RES4[p*16 + (g ^ (p&15))] = v;
    }
  }
  __syncthreads();

  float loss_pt = 0.f;

  for (int q=0;q<Qn;++q){
    const unsigned short* WHq = WH + (size_t)q*Kn*Cn;
    const unsigned short* WLq = WL + (size_t)q*Kn*Cn;
    const float* sqq = shalf + (size_t)q*Kn;

    // ---- B-frags (residual, transposed operand) from RES: persistent regs ----
    s16x8 Bh[8][2], Bl[8][2];
#pragma unroll
    for (int pt=0; pt<8; ++pt){
      int p = pt*16 + l16;
#pragma unroll
      for (int s=0;s<2;++s){
        int g0 = 8*s + quad*2;
        float4 ra = RES4[p*16 + ((g0  ) ^ (p&15))];
        float4 rb = RES4[p*16 + ((g0+1) ^ (p&15))];
        float f[8] = {ra.x,ra.y,ra.z,ra.w, rb.x,rb.y,rb.z,rb.w};
        U8 h, lo;
#pragma unroll
        for (int j=0;j<8;++j){
          unsigned short hu = bf_rtne(f[j]);
          float hf = __uint_as_float((unsigned int)hu<<16);
          h.u[j]=hu; lo.u[j]=bf_rtne(f[j]-hf);
        }
        Bh[pt][s]=h.v; Bl[pt][s]=lo.v;
      }
    }

    // ---- scan this wave's 2048-code quarter, top-2 per point ----
    float s1[8], s2[8]; int k1[8], k2[8];
#pragma unroll
    for (int pt=0;pt<8;++pt){ s1[pt]=-FLT_MAX; s2[pt]=-FLT_MAX; k1[pt]=0; k2[pt]=0; }

    int kb = wave*2048;
    const int kq = quad*4;
    s16x8 Ah0 = *(const s16x8*)(WHq + (size_t)(kb+l16)*Cn + quad*8);
    s16x8 Ah1 = *(const s16x8*)(WHq + (size_t)(kb+l16)*Cn + 32 + quad*8);
    s16x8 Al0 = *(const s16x8*)(WLq + (size_t)(kb+l16)*Cn + quad*8);
    s16x8 Al1 = *(const s16x8*)(WLq + (size_t)(kb+l16)*Cn + 32 + quad*8);
    f32x4 sv  = *(const f32x4*)(sqq + kb + kq);

    for (int kt=0; kt<128; ++kt){
      int nkb = (kt<127) ? kb+16 : kb;        // prefetch next ktile (L2-hot)
      s16x8 nAh0 = *(const s16x8*)(WHq + (size_t)(nkb+l16)*Cn + quad*8);
      s16x8 nAh1 = *(const s16x8*)(WHq + (size_t)(nkb+l16)*Cn + 32 + quad*8);
      s16x8 nAl0 = *(const s16x8*)(WLq + (size_t)(nkb+l16)*Cn + quad*8);
      s16x8 nAl1 = *(const s16x8*)(WLq + (size_t)(nkb+l16)*Cn + 32 + quad*8);
      f32x4 nsv  = *(const f32x4*)(sqq + nkb + kq);

#pragma unroll
      for (int pp=0; pp<4; ++pp){
        const int p0 = 2*pp, p1 = 2*pp+1;
        f32x4 a0 = sv, a1 = sv;                // acc init = -0.5*|c|^2
        a0 = __builtin_amdgcn_mfma_f32_16x16x32_bf16(Ah0, Bh[p0][0], a0, 0,0,0);
        a1 = __builtin_amdgcn_mfma_f32_16x16x32_bf16(Ah0, Bh[p1][0], a1, 0,0,0);
        a0 = __builtin_amdgcn_mfma_f32_16x16x32_bf16(Ah0, Bl[p0][0], a0, 0,0,0);
        a1 = __builtin_amdgcn_mfma_f32_16x16x32_bf16(Ah0, Bl[p1][0], a1, 0,0,0);
        a0 = __builtin_amdgcn_mfma_f32_16x16x32_bf16(Al0, Bh[p0][0], a0, 0,0,0);
        a1 = __builtin_amdgcn_mfma_f32_16x16x32_bf16(Al0, Bh[p1][0], a1, 0,0,0);
        a0 = __builtin_amdgcn_mfma_f32_16x16x32_bf16(Ah1, Bh[p0][1], a0, 0,0,0);
        a1 = __builtin_amdgcn_mfma_f32_16x16x32_bf16(Ah1, Bh[p1][1], a1, 0,0,0);
        a0 = __builtin_amdgcn_mfma_f32_16x16x32_bf16(Ah1, Bl[p0][1], a0, 0,0,0);
        a1 = __builtin_amdgcn_mfma_f32_16x16x32_bf16(Ah1, Bl[p1][1], a1, 0,0,0);
        a0 = __builtin_amdgcn_mfma_f32_16x16x32_bf16(Al1, Bh[p0][1], a0, 0,0,0);
        a1 = __builtin_amdgcn_mfma_f32_16x16x32_bf16(Al1, Bh[p1][1], a1, 0,0,0);
#pragma unroll
        for (int r=0;r<4;++r){                 // strict >, k ascending in r
          { float svv = a0[r]; int k = kb + kq + r;
            bool g1 = svv > s1[p0]; bool g2 = svv > s2[p0];
            float t1=s1[p0]; int t2=k1[p0];
            s2[p0] = g1 ? t1 : (g2 ? svv : s2[p0]);
            k2[p0] = g1 ? t2 : (g2 ? k   : k2[p0]);
            s1[p0] = g1 ? svv : t1;  k1[p0] = g1 ? k : t2; }
          { float svv = a1[r]; int k = kb + kq + r;
            bool g1 = svv > s1[p1]; bool g2 = svv > s2[p1];
            float t1=s1[p1]; int t2=k1[p1];
            s2[p1] = g1 ? t1 : (g2 ? svv : s2[p1]);
            k2[p1] = g1 ? t2 : (g2 ? k   : k2[p1]);
            s1[p1] = g1 ? svv : t1;  k1[p1] = g1 ? k : t2; }
        }
      }
      kb = nkb; Ah0=nAh0; Ah1=nAh1; Al0=nAl0; Al1=nAl1; sv=nsv;
    }

    // ---- cross-quad top-2 merge (quads hold disjoint code rows) ----
#pragma unroll
    for (int pt=0;pt<8;++pt){
#pragma unroll
      for (int m=16; m<=32; m<<=1){
        float o1 = __shfl_xor(s1[pt], m, 64); int ok1= __shfl_xor(k1[pt], m, 64);
        float o2 = __shfl_xor(s2[pt], m, 64); int ok2= __shfl_xor(k2[pt], m, 64);
        bool ob = (o1 > s1[pt]) || (o1==s1[pt] && ok1 < k1[pt]);
        float w1 = ob ? o1 : s1[pt]; int wk1 = ob ? ok1 : k1[pt];
        float ls = ob ? s1[pt] : o1; int lk  = ob ? k1[pt] : ok1;
        float ws = ob ? o2 : s2[pt]; int wk2 = ob ? ok2 : k2[pt];
        bool sb = (ls > ws) || (ls==ws && lk < wk2);
        s2[pt] = sb ? ls : ws; k2[pt] = sb ? lk : wk2;
        s1[pt] = w1; k1[pt] = wk1;
      }
      if (quad==0){
        int p = pt*16 + l16;
        red_s1[wave][p]=s1[pt]; red_k1[wave][p]=k1[pt];
        red_s2[wave][p]=s2[pt]; red_k2[wave][p]=k2[pt];
      }
    }
    __syncthreads();

    // ---- per-point final merge over 4 waves + margin rescore ----
    if (tid < P){
      float S1=red_s1[0][tid]; int K1=red_k1[0][tid];
      float S2=red_s2[0][tid]; int K2=red_k2[0][tid];
#pragma unroll
      for (int w=1;w<4;++w){
        float o1=red_s1[w][tid]; int ok1=red_k1[w][tid];
        float o2=red_s2[w][tid]; int ok2=red_k2[w][tid];
        bool ob = (o1 > S1) || (o1==S1 && ok1<K1);
        float w1 = ob?o1:S1; int wk1 = ob?ok1:K1;
        float ls = ob?S1:o1; int lk  = ob?K1:ok1;
        float ws = ob?o2:S2; int wk2 = ob?ok2:K2;
        bool sb = (ls>ws)||(ls==ws&&lk<wk2);
        S2 = sb?ls:ws; K2 = sb?lk:wk2; S1=w1; K1=wk1;
      }
      if (S1 - S2 < TAU){   // near-tie: exact fp32 rescore of both candidates
        float d1 = sqq[K1], d2 = sqq[K2];
        const float4* r1 = (const float4*)(cb + ((size_t)q*Kn + K1)*Cn);
        const float4* r2 = (const float4*)(cb + ((size_t)q*Kn + K2)*Cn);
#pragma unroll
        for (int g=0; g<16; ++g){
          float4 rv = RES4[tid*16 + (g ^ (tid&15))];
          float4 c1 = r1[g], c2 = r2[g];
          d1=fmaf(rv.x,c1.x,d1); d1=fmaf(rv.y,c1.y,d1);
          d1=fmaf(rv.z,c1.z,d1); d1=fmaf(rv.w,c1.w,d1);
          d2=fmaf(rv.x,c2.x,d2); d2=fmaf(rv.y,c2.y,d2);
          d2=fmaf(rv.z,c2.z,d2); d2=fmaf(rv.w,c2.w,d2);
        }
        if ( (d2 > d1) || (d2==d1 && K2<K1) ) K1 = K2;
      }
      bk_sh[tid]=K1;
      out[(size_t)(Bn*Cn*Nn) + (size_t)(b*Nn + n0 + tid)*Qn + q] = (float)K1;
    }
    __syncthreads();

    // ---- residual update (exact fp32, gathered code row L2-hot) + loss ----
    {
      int p = tid & (P-1), hc = tid>>7;
      int bk = bk_sh[p];
      const float4* crow = (const float4*)(cb + ((size_t)q*Kn + bk)*Cn) + hc*8;
#pragma unroll
      for (int l=0;l<8;++l){
        int g = hc*8 + l;
        float4 v = crow[l];
        int idx = p*16 + (g ^ (p&15));
        float4 rv = RES4[idx];
        rv.x-=v.x; rv.y-=v.y; rv.z-=v.z; rv.w-=v.w;
        RES4[idx]=rv;
        loss_pt = fmaf(rv.x,rv.x,loss_pt); loss_pt = fmaf(rv.y,rv.y,loss_pt);
        loss_pt = fmaf(rv.z,rv.z,loss_pt); loss_pt = fmaf(rv.w,rv.w,loss_pt);
      }
    }
    __syncthreads();
  } // q

  // ---- quantized = x - final residual (coalesced over p) ----
  {
    int p = tid & (P-1), hc = tid>>7;
    const float* xb = x + ((size_t)b*Cn)*Nn + n0 + p;
    float*       ob = out + ((size_t)b*Cn)*Nn + n0 + p;
#pragma unroll
    for (int l=0;l<8;++l){
      int g = hc*8+l, c = 4*g;
      float4 rv = RES4[p*16 + (g ^ (p&15))];
      ob[(size_t)(c+0)*Nn] = xb[(size_t)(c+0)*Nn] - rv.x;
      ob[(size_t)(c+1)*Nn] = xb[(size_t)(c+1)*Nn] - rv.y;
      ob[(size_t)(c+2)*Nn] = xb[(size_t)(c+2)*Nn] - rv.z;
      ob[(size_t)(c+3)*Nn] = xb[(size_t)(c+3)*Nn] - rv.w;
    }
  }
  float s = loss_pt;
#pragma unroll
  for (int off=32; off>0; off>>=1) s += __shfl_down(s, off, 64);
  if (lane==0) lsum[wave]=s;
  __syncthreads();
  if (tid==0) atomicAdd(loss_acc, lsum[0]+lsum[1]+lsum[2]+lsum[3]);
}

__global__ void final_kernel(const float* __restrict__ loss_acc,
                             float* __restrict__ out){
  out[(size_t)Bn*Cn*Nn + (size_t)Bn*Nn*Qn] =
      loss_acc[0] * (1.0f / ((float)Qn * Bn * Nn * Cn));
}

extern "C" void kernel_launch(void* const* d_in, const int* in_sizes, int n_in,
                              void* d_out, int out_size, void* d_ws, size_t ws_size,
                              hipStream_t stream) {
  const float* x  = (const float*)d_in[0];
  const float* cb = (const float*)d_in[1];
  float* out = (float*)d_out;
  float* ws  = (float*)d_ws;

  float* shalf = ws;
  unsigned short* WH = (unsigned short*)(ws + SH_F);
  unsigned short* WL = WH + W_U;
  float* loss = (float*)(WL + W_U);

  hipLaunchKernelGGL(prep_kernel, dim3((Qn*Kn)/256), dim3(256), 0, stream,
                     cb, shalf, WH, WL, loss);
  hipLaunchKernelGGL(rvq_kernel, dim3(NBLK), dim3(256), 0, stream,
                     x, cb, shalf, WH, WL, out, loss);
  hipLaunchKernelGGL(final_kernel, dim3(1), dim3(1), 0, stream, loss, out);
}

// Round 5
// 1622.387 us; speedup vs baseline: 6.3036x; 1.1223x over previous
//
#include <hip/hip_runtime.h>
#include <float.h>

// RVQ inference via MFMA: B=16, C=64, N=4096, Q=8, K=8192, fp32 in/out.
// bf16 hi/lo split distance GEMM (hh+hl+lh, fp32 acc) on mfma_f32_16x16x32_bf16.
// Round-5 deltas vs round-4:
//  - amdgpu_waves_per_eu(2,2): pin 256-VGPR budget (round-4 allocator chose 128
//    and spilled 354 MB/dispatch of scratch).
//  - Packed-index argmax: candidate k (11-bit wave-local) lives in the low
//    mantissa bits of the score; top-2 = fmed3+fmax (3 VALU ops/score vs ~8).
//    Perturbation <= |s|*2^-12 ~ 4e-3, covered by the TAU rescore net.
// ws: shalf (QK f32) | WH (QKC bf16-hi u16) | WL (lo) | loss (f32).

typedef float f32x4 __attribute__((ext_vector_type(4)));
typedef short s16x8 __attribute__((ext_vector_type(8)));

constexpr int Bn=16, Cn=64, Nn=4096, Qn=8, Kn=8192;
constexpr int P=128;                    // points per block
constexpr int NBLK = Bn*Nn/P;           // 512 blocks = 2/CU
constexpr float TAU = 0.05f;            // rescore margin (err ~5e-3 total)
constexpr size_t SH_F = (size_t)Qn*Kn;
constexpr size_t W_U  = (size_t)Qn*Kn*Cn;

union U8 { s16x8 v; unsigned short u[8]; };

__device__ __forceinline__ unsigned short bf_rtne(float x){
  unsigned int u = __float_as_uint(x);
  unsigned int r = (u + 0x7fffu + ((u>>16)&1u)) >> 16;
  return (unsigned short)r;
}

__global__ __launch_bounds__(256) void prep_kernel(const float* __restrict__ cb,
    float* __restrict__ shalf, unsigned short* __restrict__ WH,
    unsigned short* __restrict__ WL, float* __restrict__ loss){
  int r = blockIdx.x*256 + threadIdx.x;
  if (r==0) *loss = 0.f;
  const float* row = cb + (size_t)r*Cn;
  float sq = 0.f;
  for (int c=0;c<Cn;++c){
    float v = row[c]; sq = fmaf(v,v,sq);
    unsigned short h = bf_rtne(v);
    float hf = __uint_as_float((unsigned int)h<<16);
    unsigned short l = bf_rtne(v-hf);
    WH[(size_t)r*Cn+c]=h; WL[(size_t)r*Cn+c]=l;
  }
  shalf[r] = -0.5f*sq;
}

__global__ __launch_bounds__(256)
__attribute__((amdgpu_waves_per_eu(2,2)))
void rvq_kernel(
    const float* __restrict__ x, const float* __restrict__ cb,
    const float* __restrict__ shalf,
    const unsigned short* __restrict__ WH, const unsigned short* __restrict__ WL,
    float* __restrict__ out, float* __restrict__ loss_acc){
  __shared__ float4 RES4[P*16];          // res[p][4g..] at [p*16 + (g^(p&15))]
  __shared__ float  red_p1[4][P];        // packed (score|k11) per wave
  __shared__ float  red_p2[4][P];
  __shared__ int    bk_sh[P];
  __shared__ float  lsum[4];

  const int tid  = threadIdx.x;
  const int wave = tid>>6, lane = tid&63;
  const int quad = lane>>4, l16 = lane&15;
  const int b    = blockIdx.x>>5;
  const int n0   = (blockIdx.x&31)*P;

  { // ---- RES init from x[B,C,N] (coalesced over p) ----
    int p = tid & (P-1), hc = tid>>7;
    const float* xb = x + ((size_t)b*Cn)*Nn + n0 + p;
#pragma unroll
    for (int l=0;l<8;++l){
      int g = hc*8 + l;
      float4 v;
      v.x = xb[(size_t)(4*g+0)*Nn]; v.y = xb[(size_t)(4*g+1)*Nn];
      v.z = xb[(size_t)(4*g+2)*Nn]; v.w = xb[(size_t)(4*g+3)*Nn];
      RES4[p*16 + (g ^ (p&15))] = v;
    }
  }
  __syncthreads();

  float loss_pt = 0.f;

  for (int q=0;q<Qn;++q){
    const unsigned short* WHq = WH + (size_t)q*Kn*Cn;
    const unsigned short* WLq = WL + (size_t)q*Kn*Cn;
    const float* sqq = shalf + (size_t)q*Kn;

    // ---- B-frags (residual) persistent in regs: 8 ptiles x 2 Khalves x hi/lo
    s16x8 Bh[8][2], Bl[8][2];
#pragma unroll
    for (int pt=0; pt<8; ++pt){
      int p = pt*16 + l16;
#pragma unroll
      for (int s=0;s<2;++s){
        int g0 = 8*s + quad*2;
        float4 ra = RES4[p*16 + ((g0  ) ^ (p&15))];
        float4 rb = RES4[p*16 + ((g0+1) ^ (p&15))];
        float f[8] = {ra.x,ra.y,ra.z,ra.w, rb.x,rb.y,rb.z,rb.w};
        U8 h, lo;
#pragma unroll
        for (int j=0;j<8;++j){
          unsigned short hu = bf_rtne(f[j]);
          float hf = __uint_as_float((unsigned int)hu<<16);
          h.u[j]=hu; lo.u[j]=bf_rtne(f[j]-hf);
        }
        Bh[pt][s]=h.v; Bl[pt][s]=lo.v;
      }
    }

    // ---- scan this wave's 2048-code quarter; packed top-2 per point ----
    float s1[8], s2[8];
#pragma unroll
    for (int pt=0;pt<8;++pt){ s1[pt]=-FLT_MAX; s2[pt]=-FLT_MAX; }

    int kb = wave*2048;
    const int kq = quad*4;
    s16x8 Ah0 = *(const s16x8*)(WHq + (size_t)(kb+l16)*Cn + quad*8);
    s16x8 Ah1 = *(const s16x8*)(WHq + (size_t)(kb+l16)*Cn + 32 + quad*8);
    s16x8 Al0 = *(const s16x8*)(WLq + (size_t)(kb+l16)*Cn + quad*8);
    s16x8 Al1 = *(const s16x8*)(WLq + (size_t)(kb+l16)*Cn + 32 + quad*8);
    f32x4 sv  = *(const f32x4*)(sqq + kb + kq);

    for (int kt=0; kt<128; ++kt){
      int nkb = (kt<127) ? kb+16 : kb;        // prefetch next ktile (L2-hot)
      s16x8 nAh0 = *(const s16x8*)(WHq + (size_t)(nkb+l16)*Cn + quad*8);
      s16x8 nAh1 = *(const s16x8*)(WHq + (size_t)(nkb+l16)*Cn + 32 + quad*8);
      s16x8 nAl0 = *(const s16x8*)(WLq + (size_t)(nkb+l16)*Cn + quad*8);
      s16x8 nAl1 = *(const s16x8*)(WLq + (size_t)(nkb+l16)*Cn + 32 + quad*8);
      f32x4 nsv  = *(const f32x4*)(sqq + nkb + kq);

      const unsigned int kloc = (unsigned int)((kb & 2047) | kq); // 11-bit local

#pragma unroll
      for (int pp=0; pp<4; ++pp){
        const int p0 = 2*pp, p1 = 2*pp+1;
        f32x4 a0, a1;                          // C-init = -0.5|c|^2 via sv
        a0 = __builtin_amdgcn_mfma_f32_16x16x32_bf16(Ah0, Bh[p0][0], sv, 0,0,0);
        a1 = __builtin_amdgcn_mfma_f32_16x16x32_bf16(Ah0, Bh[p1][0], sv, 0,0,0);
        a0 = __builtin_amdgcn_mfma_f32_16x16x32_bf16(Ah0, Bl[p0][0], a0, 0,0,0);
        a1 = __builtin_amdgcn_mfma_f32_16x16x32_bf16(Ah0, Bl[p1][0], a1, 0,0,0);
        a0 = __builtin_amdgcn_mfma_f32_16x16x32_bf16(Al0, Bh[p0][0], a0, 0,0,0);
        a1 = __builtin_amdgcn_mfma_f32_16x16x32_bf16(Al0, Bh[p1][0], a1, 0,0,0);
        a0 = __builtin_amdgcn_mfma_f32_16x16x32_bf16(Ah1, Bh[p0][1], a0, 0,0,0);
        a1 = __builtin_amdgcn_mfma_f32_16x16x32_bf16(Ah1, Bh[p1][1], a1, 0,0,0);
        a0 = __builtin_amdgcn_mfma_f32_16x16x32_bf16(Ah1, Bl[p0][1], a0, 0,0,0);
        a1 = __builtin_amdgcn_mfma_f32_16x16x32_bf16(Ah1, Bl[p1][1], a1, 0,0,0);
        a0 = __builtin_amdgcn_mfma_f32_16x16x32_bf16(Al1, Bh[p0][1], a0, 0,0,0);
        a1 = __builtin_amdgcn_mfma_f32_16x16x32_bf16(Al1, Bh[p1][1], a1, 0,0,0);
#pragma unroll
        for (int r=0;r<4;++r){
          // pack index into low 11 mantissa bits: 1 v_and_or + fmed3 + fmax
          float pv0 = __uint_as_float((__float_as_uint(a0[r]) & 0xFFFFF800u)
                                      | (kloc + (unsigned)r));
          float pv1 = __uint_as_float((__float_as_uint(a1[r]) & 0xFFFFF800u)
                                      | (kloc + (unsigned)r));
          float n20 = __builtin_amdgcn_fmed3f(pv0, s1[p0], s2[p0]);
          s1[p0] = fmaxf(s1[p0], pv0); s2[p0] = n20;
          float n21 = __builtin_amdgcn_fmed3f(pv1, s1[p1], s2[p1]);
          s1[p1] = fmaxf(s1[p1], pv1); s2[p1] = n21;
        }
      }
      kb = nkb; Ah0=nAh0; Ah1=nAh1; Al0=nAl0; Al1=nAl1; sv=nsv;
    }

    // ---- cross-quad top-2 merge in packed domain (k travels in the bits) ----
#pragma unroll
    for (int pt=0;pt<8;++pt){
#pragma unroll
      for (int m=16; m<=32; m<<=1){
        float o1 = __shfl_xor(s1[pt], m, 64);
        float o2 = __shfl_xor(s2[pt], m, 64);
        float n1 = fmaxf(s1[pt], o1);
        float n2 = fmaxf(fminf(s1[pt], o1), fmaxf(s2[pt], o2));
        s1[pt]=n1; s2[pt]=n2;
      }
      if (quad==0){
        int p = pt*16 + l16;
        red_p1[wave][p]=s1[pt]; red_p2[wave][p]=s2[pt];
      }
    }
    __syncthreads();

    // ---- per-point 4-wave merge (track wave origin) + margin rescore ----
    if (tid < P){
      float S1 = red_p1[0][tid]; int W1 = 0;
      float S2 = red_p2[0][tid]; int W2 = 0;
#pragma unroll
      for (int w=1; w<4; ++w){
        float o1 = red_p1[w][tid], o2 = red_p2[w][tid];
        if (o1 > S1){
          if (S1 > o2){ S2 = S1; W2 = W1; } else { S2 = o2; W2 = w; }
          S1 = o1; W1 = w;
        } else if (o1 > S2){ S2 = o1; W2 = w; }
      }
      int K1 = (W1<<11) | (int)(__float_as_uint(S1) & 2047u);
      int K2 = (W2<<11) | (int)(__float_as_uint(S2) & 2047u);
      if (S1 - S2 < TAU){   // near-tie: exact fp32 rescore of both candidates
        float d1 = sqq[K1], d2 = sqq[K2];
        const float4* r1 = (const float4*)(cb + ((size_t)q*Kn + K1)*Cn);
        const float4* r2 = (const float4*)(cb + ((size_t)q*Kn + K2)*Cn);
#pragma unroll
        for (int g=0; g<16; ++g){
          float4 rv = RES4[tid*16 + (g ^ (tid&15))];
          float4 c1 = r1[g], c2 = r2[g];
          d1=fmaf(rv.x,c1.x,d1); d1=fmaf(rv.y,c1.y,d1);
          d1=fmaf(rv.z,c1.z,d1); d1=fmaf(rv.w,c1.w,d1);
          d2=fmaf(rv.x,c2.x,d2); d2=fmaf(rv.y,c2.y,d2);
          d2=fmaf(rv.z,c2.z,d2); d2=fmaf(rv.w,c2.w,d2);
        }
        if ( (d2 > d1) || (d2==d1 && K2<K1) ) K1 = K2;
      }
      bk_sh[tid]=K1;
      out[(size_t)(Bn*Cn*Nn) + (size_t)(b*Nn + n0 + tid)*Qn + q] = (float)K1;
    }
    __syncthreads();

    // ---- residual update (exact fp32, winner row L2-hot) + loss ----
    {
      int p = tid & (P-1), hc = tid>>7;
      int bk = bk_sh[p];
      const float4* crow = (const float4*)(cb + ((size_t)q*Kn + bk)*Cn) + hc*8;
#pragma unroll
      for (int l=0;l<8;++l){
        int g = hc*8 + l;
        float4 v = crow[l];
        int idx = p*16 + (g ^ (p&15));
        float4 rv = RES4[idx];
        rv.x-=v.x; rv.y-=v.y; rv.z-=v.z; rv.w-=v.w;
        RES4[idx]=rv;
        loss_pt = fmaf(rv.x,rv.x,loss_pt); loss_pt = fmaf(rv.y,rv.y,loss_pt);
        loss_pt = fmaf(rv.z,rv.z,loss_pt); loss_pt = fmaf(rv.w,rv.w,loss_pt);
      }
    }
    __syncthreads();
  } // q

  // ---- quantized = x - final residual (coalesced over p) ----
  {
    int p = tid & (P-1), hc = tid>>7;
    const float* xb = x + ((size_t)b*Cn)*Nn + n0 + p;
    float*       ob = out + ((size_t)b*Cn)*Nn + n0 + p;
#pragma unroll
    for (int l=0;l<8;++l){
      int g = hc*8+l, c = 4*g;
      float4 rv = RES4[p*16 + (g ^ (p&15))];
      ob[(size_t)(c+0)*Nn] = xb[(size_t)(c+0)*Nn] - rv.x;
      ob[(size_t)(c+1)*Nn] = xb[(size_t)(c+1)*Nn] - rv.y;
      ob[(size_t)(c+2)*Nn] = xb[(size_t)(c+2)*Nn] - rv.z;
      ob[(size_t)(c+3)*Nn] = xb[(size_t)(c+3)*Nn] - rv.w;
    }
  }
  float s = loss_pt;
#pragma unroll
  for (int off=32; off>0; off>>=1) s += __shfl_down(s, off, 64);
  if (lane==0) lsum[wave]=s;
  __syncthreads();
  if (tid==0) atomicAdd(loss_acc, lsum[0]+lsum[1]+lsum[2]+lsum[3]);
}

__global__ void final_kernel(const float* __restrict__ loss_acc,
                             float* __restrict__ out){
  out[(size_t)Bn*Cn*Nn + (size_t)Bn*Nn*Qn] =
      loss_acc[0] * (1.0f / ((float)Qn * Bn * Nn * Cn));
}

extern "C" void kernel_launch(void* const* d_in, const int* in_sizes, int n_in,
                              void* d_out, int out_size, void* d_ws, size_t ws_size,
                              hipStream_t stream) {
  const float* x  = (const float*)d_in[0];
  const float* cb = (const float*)d_in[1];
  float* out = (float*)d_out;
  float* ws  = (float*)d_ws;

  float* shalf = ws;
  unsigned short* WH = (unsigned short*)(ws + SH_F);
  unsigned short* WL = WH + W_U;
  float* loss = (float*)(WL + W_U);

  hipLaunchKernelGGL(prep_kernel, dim3((Qn*Kn)/256), dim3(256), 0, stream,
                     cb, shalf, WH, WL, loss);
  hipLaunchKernelGGL(rvq_kernel, dim3(NBLK), dim3(256), 0, stream,
                     x, cb, shalf, WH, WL, out, loss);
  hipLaunchKernelGGL(final_kernel, dim3(1), dim3(1), 0, stream, loss, out);
}